// Round 8
// baseline (203.363 us; speedup 1.0000x reference)
//
#include <hip/hip_runtime.h>

#define T_DIM 8192
#define N_DIM 8
#define C_DIM 64
#define KB    2048
#define NT    (N_DIM * T_DIM)        // 65536 rows
#define TOTX  ((size_t)NT * C_DIM)   // 4194304 elements
#define ROWS_BLK 128
#define NBLK  (NT / ROWS_BLK)        // 512 blocks
#define LISTCAP 8192
#define TAU   1e-3f

// Scratch inside out's x_d region (out + NT), overwritten LAST by xd_kernel.
// Offsets in FLOAT units from out+NT:
#define SCR_COUNT 0                   // int
#define SCR_LIST  16                  // int[8192]          -> ends 8208
#define SCR_PART  8448                // float[512][8]      -> ends 12544
#define SCR_KNS   16384               // float[2048]        -> ends 18432
#define SCR_K     32768               // f16x8[16][2048] (512 KB) -> ends 163840

typedef _Float16 half_t;
typedef _Float16 f16x8 __attribute__((ext_vector_type(8)));
typedef float    f32x16 __attribute__((ext_vector_type(16)));

// LDS byte offsets (argmin kernel)
#define L_BUF0 0        // 32 KB  (hi 16K | lo 16K)   [overlaid by xhi/xlo early]
#define L_BUF1 32768    // 32 KB
#define L_KNS  65536    // 8 KB
#define L_SXH  73728    // float[2][128]
#define L_SXXH 74752    // float[2][128]
#define L_WACC 75776    // float[4][8]
#define L_TOT  75904

__device__ __forceinline__ void gload_lds16(const void* g, void* l) {
    __builtin_amdgcn_global_load_lds(
        (const __attribute__((address_space(1))) unsigned int*)g,
        (__attribute__((address_space(3))) unsigned int*)l, 16, 0, 0);
}

#define WAITV8() asm volatile("s_waitcnt vmcnt(8)" ::: "memory")
#define WAITV0() asm volatile("s_waitcnt vmcnt(0)" ::: "memory")
#define WAITL0() asm volatile("s_waitcnt lgkmcnt(0)" ::: "memory")
#define BAR()    __builtin_amdgcn_s_barrier()

// numpy pairwise sum (n=64) of squares for the np-exact fixup.
__device__ __forceinline__ float np_sumsq64(const float* __restrict__ a) {
    float r[8];
    #pragma unroll
    for (int j = 0; j < 8; ++j) r[j] = __fmul_rn(a[j], a[j]);
    #pragma unroll
    for (int i = 8; i < 64; i += 8)
        #pragma unroll
        for (int j = 0; j < 8; ++j)
            r[j] = __fadd_rn(r[j], __fmul_rn(a[i + j], a[i + j]));
    return __fadd_rn(__fadd_rn(__fadd_rn(r[0], r[1]), __fadd_rn(r[2], r[3])),
                     __fadd_rn(__fadd_rn(r[4], r[5]), __fadd_rn(r[6], r[7])));
}

// ------------------------------------------------------------------ k prep ----
// Layout: kscr[ch][0:1024) = hi slots [slot][bin], [1024:2048) = lo slots.
// hi = -2*k_hi (exact), lo = -4096*(k - k_hi) rounded once. Also ||k||^2.
__global__ __launch_bounds__(256) void kprep_kernel(const float* __restrict__ k,
                                                    float* __restrict__ out) {
    float* base = out + NT;
    const int bin = blockIdx.x * 256 + threadIdx.x;   // grid 8 -> 2048
    if (bin == 0) ((int*)base)[SCR_COUNT] = 0;

    float kv[64];
    #pragma unroll
    for (int i = 0; i < 16; ++i)
        *(float4*)&kv[i * 4] = *(const float4*)(k + (size_t)bin * 64 + i * 4);

    float kn = 0.f;
    #pragma unroll
    for (int c = 0; c < 64; ++c) kn = fmaf(kv[c], kv[c], kn);
    base[SCR_KNS + bin] = kn;

    f16x8* kscr = (f16x8*)(base + SCR_K);
    const int ch = bin >> 7, b127 = bin & 127;
    #pragma unroll
    for (int slot = 0; slot < 8; ++slot) {
        f16x8 h8, l8;
        #pragma unroll
        for (int e = 0; e < 8; ++e) {
            float xv = kv[slot * 8 + e];
            half_t hh = (half_t)xv;
            h8[e] = (half_t)(-2.f * (float)hh);
            l8[e] = (half_t)(-4096.f * (xv - (float)hh));
        }
        kscr[(size_t)ch * 2048 + slot * 128 + b127]        = h8;
        kscr[(size_t)ch * 2048 + 1024 + slot * 128 + b127] = l8;
    }
}

// ------------------------------------------------------------------ argmin ----
// 256 threads (4 waves), 128 rows/block. Double-buffered async k staging with
// counted vmcnt; [slot][bin] conflict-free LDS; kn folded into acc init.
__global__ __launch_bounds__(256, 2) void argmin_kernel(const float* __restrict__ x,
                                                        const float* __restrict__ mask,
                                                        float* __restrict__ out) {
    __shared__ __align__(16) char smem[L_TOT];

    float* base = out + NT;
    const int tid = threadIdx.x;
    const int l   = tid & 63, w = tid >> 6;
    const int col = l & 31, kg = l >> 5;
    const int r0  = blockIdx.x * ROWS_BLK;
    const int n   = r0 >> 13;
    const int t0  = r0 & (T_DIM - 1);

    float* kns_s = (float*)(smem + L_KNS);
    float* sxh   = (float*)(smem + L_SXH);
    float* sxxh  = (float*)(smem + L_SXXH);
    float* wacc  = (float*)(smem + L_WACC);
    f16x8* xhi_s = (f16x8*)(smem + L_BUF0);           // [8 slots][128 rows]
    f16x8* xlo_s = (f16x8*)(smem + L_BUF0 + 16384);

    // stage ||k||^2 into LDS (8 per thread)
    #pragma unroll
    for (int i = 0; i < 8; ++i)
        kns_s[i * 256 + tid] = base[SCR_KNS + i * 256 + tid];

    // fused x load + f16 hi/lo split (thread: row = tid&127, c-half = tid>>7)
    {
        const int row = tid & 127, chalf = tid >> 7;
        float xv[32];
        #pragma unroll
        for (int j = 0; j < 32; ++j)
            xv[j] = x[((size_t)n * C_DIM + chalf * 32 + j) * T_DIM + t0 + row];
        float sx = 0.f, sxx = 0.f;
        #pragma unroll
        for (int j = 0; j < 32; ++j) { sx += xv[j]; sxx = fmaf(xv[j], xv[j], sxx); }
        sxh[chalf * 128 + row]  = sx;
        sxxh[chalf * 128 + row] = sxx;
        #pragma unroll
        for (int j4 = 0; j4 < 4; ++j4) {
            f16x8 h8, l8;
            #pragma unroll
            for (int e = 0; e < 8; ++e) {
                float v = xv[j4 * 8 + e];
                half_t hh = (half_t)v;
                h8[e] = hh;
                l8[e] = (half_t)(2048.f * (v - (float)hh));
            }
            const int slot = chalf * 4 + j4;
            xhi_s[slot * 128 + row] = h8;
            xlo_s[slot * 128 + row] = l8;
        }
    }
    WAITL0(); BAR();

    // A fragments (persistent registers)
    const int arow = w * 32 + col;
    f16x8 a_hi[4], a_lo[4];
    #pragma unroll
    for (int s = 0; s < 4; ++s) {
        a_hi[s] = xhi_s[(2 * s + kg) * 128 + arow];
        a_lo[s] = xlo_s[(2 * s + kg) * 128 + arow];
    }
    WAITL0(); BAR();    // all waves done reading buf0 region

    f16x8* kscr = (f16x8*)(base + SCR_K);
    auto stage = [&](int ch, int bufoff) {
        const f16x8* src = kscr + (size_t)ch * 2048;
        char* dst = smem + bufoff;
        #pragma unroll
        for (int i = 0; i < 8; ++i) {
            int idx = i * 256 + tid;
            gload_lds16(src + idx, dst + idx * 16);
        }
    };

    float bestv[16], best2v[16];
    int   bestb[16];
    #pragma unroll
    for (int r = 0; r < 16; ++r) {
        bestv[r] = __builtin_inff(); best2v[r] = __builtin_inff(); bestb[r] = 0;
    }

    auto compute = [&](int ch, int bufoff) {
        const f16x8* bhi = (const f16x8*)(smem + bufoff);
        const f16x8* blo = bhi + 1024;
        #pragma unroll
        for (int t4 = 0; t4 < 4; ++t4) {
            const int lrow = t4 * 32 + col;
            const float kn = kns_s[ch * 128 + lrow];
            f16x8 b_hi[4], b_lo[4];
            #pragma unroll
            for (int s = 0; s < 4; ++s) {
                b_hi[s] = bhi[(2 * s + kg) * 128 + lrow];
                b_lo[s] = blo[(2 * s + kg) * 128 + lrow];
            }
            f32x16 acc1, acc2;
            #pragma unroll
            for (int r = 0; r < 16; ++r) { acc1[r] = kn; acc2[r] = 0.f; }
            #pragma unroll
            for (int s = 0; s < 4; ++s) {
                acc1 = __builtin_amdgcn_mfma_f32_32x32x16_f16(a_hi[s], b_hi[s], acc1, 0, 0, 0);
                acc2 = __builtin_amdgcn_mfma_f32_32x32x16_f16(a_hi[s], b_lo[s], acc2, 0, 0, 0);
                acc2 = __builtin_amdgcn_mfma_f32_32x32x16_f16(a_lo[s], b_hi[s], acc2, 0, 0, 0);
            }
            const int binf = ch * 128 + lrow;
            #pragma unroll
            for (int r = 0; r < 16; ++r) {
                float sv = fmaf(acc2[r], 4.8828125e-4f, acc1[r]);  // kn - 2*dot
                best2v[r] = fminf(best2v[r], fmaxf(sv, bestv[r]));
                if (sv < bestv[r]) { bestv[r] = sv; bestb[r] = binf; }
            }
        }
    };

    WAITV0();                 // clean vmcnt baseline
    stage(0, L_BUF0);
    stage(1, L_BUF1);

    for (int ch = 0; ch < 14; ++ch) {
        const int p = (ch & 1) ? L_BUF1 : L_BUF0;
        WAITV8(); BAR();      // this chunk's loads landed (all waves)
        compute(ch, p);
        WAITL0(); BAR();      // all waves done reading buffer p
        stage(ch + 2, p);
    }
    WAITV8(); BAR(); compute(14, L_BUF0);
    WAITV0(); BAR(); compute(15, L_BUF1);

    // merge across the 32 column-lanes of each half, tracking 2nd-best
    #pragma unroll
    for (int off = 1; off <= 16; off <<= 1) {
        #pragma unroll
        for (int r = 0; r < 16; ++r) {
            float ov = __shfl_xor(bestv[r], off, 64);
            int   ob = __shfl_xor(bestb[r], off, 64);
            float o2 = __shfl_xor(best2v[r], off, 64);
            float mx = fmaxf(bestv[r], ov);
            best2v[r] = fminf(fminf(best2v[r], o2), mx);
            if (ov < bestv[r] || (ov == bestv[r] && ob < bestb[r])) {
                bestv[r] = ov; bestb[r] = ob;
            }
        }
    }

    // write-out (lanes col==0 of each half own 16 rows each)
    float s0 = 0.f, s1 = 0.f, s2 = 0.f, s3 = 0.f, s4 = 0.f;
    if (col == 0) {
        int* countp = (int*)base + SCR_COUNT;
        int* listp  = (int*)base + SCR_LIST;
        #pragma unroll
        for (int r = 0; r < 16; ++r) {
            const int row_loc = w * 32 + 4 * kg + (r & 3) + 8 * (r >> 2);
            const int grow = r0 + row_loc;
            out[grow] = (float)bestb[r];
            if (best2v[r] - bestv[r] < TAU) {
                int idx = atomicAdd(countp, 1);
                if (idx < LISTCAP) listp[idx] = grow;
            }
            const float m   = mask[grow];
            const float sxx = sxxh[row_loc] + sxxh[128 + row_loc];
            const float d2  = sxx + bestv[r];
            s0 = fmaf(m, d2, s0); s1 += d2; s2 += m;
            s3 += sxh[row_loc] + sxh[128 + row_loc];
            s4 += sxx;
        }
    }
    s0 += __shfl_xor(s0, 32, 64);
    s1 += __shfl_xor(s1, 32, 64);
    s2 += __shfl_xor(s2, 32, 64);
    s3 += __shfl_xor(s3, 32, 64);
    s4 += __shfl_xor(s4, 32, 64);
    if (l == 0) {
        wacc[w * 8 + 0] = s0; wacc[w * 8 + 1] = s1; wacc[w * 8 + 2] = s2;
        wacc[w * 8 + 3] = s3; wacc[w * 8 + 4] = s4;
    }
    WAITL0(); BAR();
    if (tid == 0) {
        float* partials = base + SCR_PART;
        #pragma unroll
        for (int q = 0; q < 5; ++q)
            partials[(size_t)blockIdx.x * 8 + q] =
                wacc[0 * 8 + q] + wacc[1 * 8 + q] + wacc[2 * 8 + q] + wacc[3 * 8 + q];
    }
}

// ------------------------------------------------------------------ fixup ----
// np-f32-exact recompute of flagged near-tie rows (first-occurrence argmin).
__global__ __launch_bounds__(256) void fixup_kernel(const float* __restrict__ x,
                                                    const float* __restrict__ k,
                                                    float* __restrict__ out) {
    __shared__ float xv[C_DIM];
    __shared__ float sxxs;
    __shared__ float redv[4];
    __shared__ int   redb[4];
    const int tid = threadIdx.x;
    const int* count    = (const int*)(out + NT) + SCR_COUNT;
    const int* flaglist = (const int*)(out + NT) + SCR_LIST;
    int cnt = *count;
    if (cnt > LISTCAP) cnt = LISTCAP;

    for (int it = blockIdx.x; it < cnt; it += gridDim.x) {
        const int row = flaglist[it];
        const int n = row >> 13, t = row & (T_DIM - 1);
        if (tid < C_DIM)
            xv[tid] = x[((size_t)n * C_DIM + tid) * T_DIM + t];
        __syncthreads();
        if (tid == 0) sxxs = np_sumsq64(xv);
        __syncthreads();
        const float xx = sxxs;

        float bv = __builtin_inff();
        int   bb = 0x7fffffff;
        for (int b = tid; b < KB; b += 256) {
            const float* kr = k + (size_t)b * C_DIM;
            float dot = 0.f;
            #pragma unroll
            for (int c = 0; c < C_DIM; ++c)
                dot = fmaf(xv[c], kr[c], dot);
            float kk = np_sumsq64(kr);
            float d  = __fadd_rn(__fsub_rn(xx, __fadd_rn(dot, dot)), kk);
            if (d < bv) { bv = d; bb = b; }
        }
        #pragma unroll
        for (int off = 1; off <= 32; off <<= 1) {
            float ov = __shfl_xor(bv, off, 64);
            int   ob = __shfl_xor(bb, off, 64);
            if (ov < bv || (ov == bv && ob < bb)) { bv = ov; bb = ob; }
        }
        const int wid = tid >> 6, lane = tid & 63;
        if (lane == 0) { redv[wid] = bv; redb[wid] = bb; }
        __syncthreads();
        if (tid == 0) {
            float fv = redv[0]; int fb = redb[0];
            #pragma unroll
            for (int wq = 1; wq < 4; ++wq) {
                if (redv[wq] < fv || (redv[wq] == fv && redb[wq] < fb)) {
                    fv = redv[wq]; fb = redb[wq];
                }
            }
            out[row] = (float)fb;
        }
        __syncthreads();
    }
}

// ------------------------------------------------------------- finalize ----
__global__ __launch_bounds__(256) void finalize_kernel(float* __restrict__ out) {
    const float* partials = (out + NT) + SCR_PART;
    const int tid = threadIdx.x;
    double vals[5] = {0, 0, 0, 0, 0};
    for (int i = tid; i < NBLK; i += 256)
        #pragma unroll
        for (int q = 0; q < 5; ++q) vals[q] += (double)partials[(size_t)i * 8 + q];
    #pragma unroll
    for (int off = 1; off <= 32; off <<= 1)
        #pragma unroll
        for (int q = 0; q < 5; ++q) vals[q] += __shfl_xor(vals[q], off, 64);
    __shared__ double sred[4][5];
    const int wid = tid >> 6, lane = tid & 63;
    if (lane == 0)
        for (int q = 0; q < 5; ++q) sred[wid][q] = vals[q];
    __syncthreads();
    if (tid == 0) {
        double cm  = sred[0][0] + sred[1][0] + sred[2][0] + sred[3][0];
        double fs  = sred[0][1] + sred[1][1] + sred[2][1] + sred[3][1];
        double ms  = sred[0][2] + sred[1][2] + sred[2][2] + sred[3][2];
        double sx  = sred[0][3] + sred[1][3] + sred[2][3] + sred[3][3];
        double sxx = sred[0][4] + sred[1][4] + sred[2][4] + sred[3][4];
        double sz  = (double)TOTX;
        out[NT + TOTX + 0] = (float)(cm / (ms * (double)C_DIM));
        out[NT + TOTX + 1] = (float)(fs / (double)NT);
        out[NT + TOTX + 2] = (float)sqrt(fmax(0.0, (sxx - sx * sx / sz) / sz));
    }
}

// --------------------------------------------------------------------- x_d ----
// Runs LAST: overwrites the scratch region with real x_d values.
__global__ __launch_bounds__(256) void xd_kernel(const float* __restrict__ mask,
                                                 const float* __restrict__ k,
                                                 float* __restrict__ out) {
    const int row = blockIdx.x * 256 + threadIdx.x;
    const int n = row >> 13, t = row & (T_DIM - 1);
    const int b = (int)out[row];
    const float m = mask[row];
    const float* kr = k + (size_t)b * C_DIM;
    float* xd = out + NT;
    #pragma unroll
    for (int c = 0; c < C_DIM; ++c)
        xd[((size_t)n * C_DIM + c) * T_DIM + t] = kr[c] * m;
}

// ----------------------------------------------------------------- launch ----
extern "C" void kernel_launch(void* const* d_in, const int* in_sizes, int n_in,
                              void* d_out, int out_size, void* d_ws, size_t ws_size,
                              hipStream_t stream) {
    (void)in_sizes; (void)n_in; (void)out_size; (void)d_ws; (void)ws_size;
    const float* x    = (const float*)d_in[0];
    const float* mask = (const float*)d_in[1];
    const float* k    = (const float*)d_in[2];
    float* out = (float*)d_out;

    kprep_kernel<<<KB / 256, 256, 0, stream>>>(k, out);
    argmin_kernel<<<NBLK, 256, 0, stream>>>(x, mask, out);
    fixup_kernel<<<64, 256, 0, stream>>>(x, k, out);
    finalize_kernel<<<1, 256, 0, stream>>>(out);
    xd_kernel<<<NT / 256, 256, 0, stream>>>(mask, k, out);
}

// Round 9
// 134.070 us; speedup vs baseline: 1.5168x; 1.5168x over previous
//
#include <hip/hip_runtime.h>

#define T_DIM 8192
#define N_DIM 8
#define C_DIM 64
#define KB    2048
#define NT    (N_DIM * T_DIM)        // 65536 rows
#define TOTX  ((size_t)NT * C_DIM)   // 4194304 elements
#define ROWS_BLK 128
#define NBLK  (NT / ROWS_BLK)        // 512 blocks
#define LISTCAP 8192
#define TAU   1e-3f

// Scratch inside out's x_d region (out + NT), overwritten LAST by xd_kernel.
// Offsets in FLOAT units from out+NT:
#define SCR_COUNT 0                   // int
#define SCR_LIST  16                  // int[8192]          -> ends 8208
#define SCR_PART  8448                // float[512][8]      -> ends 12544
#define SCR_KNS   16384               // float[2048]        -> ends 18432
#define SCR_K     32768               // f16x8[16][2048] (512 KB) -> ends 163840

typedef _Float16 half_t;
typedef _Float16 f16x8 __attribute__((ext_vector_type(8)));
typedef float    f32x16 __attribute__((ext_vector_type(16)));

// LDS byte offsets (argmin kernel)
#define L_BUF0 0        // 32 KB  (hi 16K | lo 16K)   [overlaid by xhi/xlo early]
#define L_BUF1 32768    // 32 KB
#define L_KNS  65536    // 8 KB
#define L_SXH  73728    // float[2][128]
#define L_SXXH 74752    // float[2][128]
#define L_WACC 75776    // float[4][8]
#define L_TOT  75904

#define WAITL0() asm volatile("s_waitcnt lgkmcnt(0)" ::: "memory")
#define BAR()    __builtin_amdgcn_s_barrier()

// numpy pairwise sum (n=64) of squares for the np-exact fixup.
__device__ __forceinline__ float np_sumsq64(const float* __restrict__ a) {
    float r[8];
    #pragma unroll
    for (int j = 0; j < 8; ++j) r[j] = __fmul_rn(a[j], a[j]);
    #pragma unroll
    for (int i = 8; i < 64; i += 8)
        #pragma unroll
        for (int j = 0; j < 8; ++j)
            r[j] = __fadd_rn(r[j], __fmul_rn(a[i + j], a[i + j]));
    return __fadd_rn(__fadd_rn(__fadd_rn(r[0], r[1]), __fadd_rn(r[2], r[3])),
                     __fadd_rn(__fadd_rn(r[4], r[5]), __fadd_rn(r[6], r[7])));
}

// ------------------------------------------------------------------ k prep ----
// Layout: kscr[ch][0:1024) = hi slots [slot][bin], [1024:2048) = lo slots.
// hi = -2*k_hi (exact), lo = -4096*(k - k_hi) rounded once. Also ||k||^2.
__global__ __launch_bounds__(256) void kprep_kernel(const float* __restrict__ k,
                                                    float* __restrict__ out) {
    float* base = out + NT;
    const int bin = blockIdx.x * 256 + threadIdx.x;   // grid 8 -> 2048
    if (bin == 0) ((int*)base)[SCR_COUNT] = 0;

    float kv[64];
    #pragma unroll
    for (int i = 0; i < 16; ++i)
        *(float4*)&kv[i * 4] = *(const float4*)(k + (size_t)bin * 64 + i * 4);

    float kn = 0.f;
    #pragma unroll
    for (int c = 0; c < 64; ++c) kn = fmaf(kv[c], kv[c], kn);
    base[SCR_KNS + bin] = kn;

    f16x8* kscr = (f16x8*)(base + SCR_K);
    const int ch = bin >> 7, b127 = bin & 127;
    #pragma unroll
    for (int slot = 0; slot < 8; ++slot) {
        f16x8 h8, l8;
        #pragma unroll
        for (int e = 0; e < 8; ++e) {
            float xv = kv[slot * 8 + e];
            half_t hh = (half_t)xv;
            h8[e] = (half_t)(-2.f * (float)hh);
            l8[e] = (half_t)(-4096.f * (xv - (float)hh));
        }
        kscr[(size_t)ch * 2048 + slot * 128 + b127]        = h8;
        kscr[(size_t)ch * 2048 + 1024 + slot * 128 + b127] = l8;
    }
}

// ------------------------------------------------------------------ argmin ----
// 256 threads (4 waves), 128 rows/block. Reg-staged k chunks (L2-cached
// broadcast), double LDS buffer, one barrier per chunk; loads for chunk
// ch+2 issued during compute of ch (full-iteration latency hiding).
__global__ __launch_bounds__(256, 2) void argmin_kernel(const float* __restrict__ x,
                                                        const float* __restrict__ mask,
                                                        float* __restrict__ out) {
    __shared__ __align__(16) char smem[L_TOT];

    float* base = out + NT;
    const int tid = threadIdx.x;
    const int l   = tid & 63, w = tid >> 6;
    const int col = l & 31, kg = l >> 5;
    const int r0  = blockIdx.x * ROWS_BLK;
    const int n   = r0 >> 13;
    const int t0  = r0 & (T_DIM - 1);

    float* kns_s = (float*)(smem + L_KNS);
    float* sxh   = (float*)(smem + L_SXH);
    float* sxxh  = (float*)(smem + L_SXXH);
    float* wacc  = (float*)(smem + L_WACC);
    f16x8* xhi_s = (f16x8*)(smem + L_BUF0);           // [8 slots][128 rows]
    f16x8* xlo_s = (f16x8*)(smem + L_BUF0 + 16384);

    // stage ||k||^2 into LDS (8 per thread)
    #pragma unroll
    for (int i = 0; i < 8; ++i)
        kns_s[i * 256 + tid] = base[SCR_KNS + i * 256 + tid];

    // fused x load + f16 hi/lo split (thread: row = tid&127, c-half = tid>>7)
    {
        const int row = tid & 127, chalf = tid >> 7;
        float xv[32];
        #pragma unroll
        for (int j = 0; j < 32; ++j)
            xv[j] = x[((size_t)n * C_DIM + chalf * 32 + j) * T_DIM + t0 + row];
        float sx = 0.f, sxx = 0.f;
        #pragma unroll
        for (int j = 0; j < 32; ++j) { sx += xv[j]; sxx = fmaf(xv[j], xv[j], sxx); }
        sxh[chalf * 128 + row]  = sx;
        sxxh[chalf * 128 + row] = sxx;
        #pragma unroll
        for (int j4 = 0; j4 < 4; ++j4) {
            f16x8 h8, l8;
            #pragma unroll
            for (int e = 0; e < 8; ++e) {
                float v = xv[j4 * 8 + e];
                half_t hh = (half_t)v;
                h8[e] = hh;
                l8[e] = (half_t)(2048.f * (v - (float)hh));
            }
            const int slot = chalf * 4 + j4;
            xhi_s[slot * 128 + row] = h8;
            xlo_s[slot * 128 + row] = l8;
        }
    }
    WAITL0(); BAR();

    // A fragments (persistent registers)
    const int arow = w * 32 + col;
    f16x8 a_hi[4], a_lo[4];
    #pragma unroll
    for (int s = 0; s < 4; ++s) {
        a_hi[s] = xhi_s[(2 * s + kg) * 128 + arow];
        a_lo[s] = xlo_s[(2 * s + kg) * 128 + arow];
    }
    WAITL0(); BAR();    // all waves done reading buf0 region

    const f16x8* kscr = (const f16x8*)(base + SCR_K);
    f16x8 rk[8];
    auto kload = [&](int ch) {
        const f16x8* src = kscr + (size_t)ch * 2048;
        #pragma unroll
        for (int i = 0; i < 8; ++i) rk[i] = src[i * 256 + tid];
    };
    auto kwrite = [&](int bufoff) {
        f16x8* dst = (f16x8*)(smem + bufoff);
        #pragma unroll
        for (int i = 0; i < 8; ++i) dst[i * 256 + tid] = rk[i];
    };

    float bestv[16], best2v[16];
    int   bestb[16];
    #pragma unroll
    for (int r = 0; r < 16; ++r) {
        bestv[r] = __builtin_inff(); best2v[r] = __builtin_inff(); bestb[r] = 0;
    }

    auto compute = [&](int ch, int bufoff) {
        const f16x8* bhi = (const f16x8*)(smem + bufoff);
        const f16x8* blo = bhi + 1024;
        #pragma unroll
        for (int t4 = 0; t4 < 4; ++t4) {
            const int lrow = t4 * 32 + col;
            const float kn = kns_s[ch * 128 + lrow];
            f16x8 b_hi[4], b_lo[4];
            #pragma unroll
            for (int s = 0; s < 4; ++s) {
                b_hi[s] = bhi[(2 * s + kg) * 128 + lrow];
                b_lo[s] = blo[(2 * s + kg) * 128 + lrow];
            }
            f32x16 acc1, acc2;
            #pragma unroll
            for (int r = 0; r < 16; ++r) { acc1[r] = kn; acc2[r] = 0.f; }
            #pragma unroll
            for (int s = 0; s < 4; ++s) {
                acc1 = __builtin_amdgcn_mfma_f32_32x32x16_f16(a_hi[s], b_hi[s], acc1, 0, 0, 0);
                acc2 = __builtin_amdgcn_mfma_f32_32x32x16_f16(a_hi[s], b_lo[s], acc2, 0, 0, 0);
                acc2 = __builtin_amdgcn_mfma_f32_32x32x16_f16(a_lo[s], b_hi[s], acc2, 0, 0, 0);
            }
            const int binf = ch * 128 + lrow;
            #pragma unroll
            for (int r = 0; r < 16; ++r) {
                float sv = fmaf(acc2[r], 4.8828125e-4f, acc1[r]);  // kn - 2*dot
                best2v[r] = fminf(best2v[r], fmaxf(sv, bestv[r]));
                if (sv < bestv[r]) { bestv[r] = sv; bestb[r] = binf; }
            }
        }
    };

    // pipeline prologue: buf0 <- ch0; rk holds ch1
    kload(0);
    kwrite(L_BUF0);            // compiler inserts the exact vmcnt wait
    kload(1);
    WAITL0(); BAR();           // buf0 visible to all waves

    for (int ch = 0; ch < 16; ++ch) {
        const int p = (ch & 1) ? L_BUF1 : L_BUF0;
        const int q = (ch & 1) ? L_BUF0 : L_BUF1;
        if (ch < 15) {
            kwrite(q);         // stage ch+1 (vmcnt wait auto-inserted)
            if (ch < 14) kload(ch + 2);   // in flight across the barrier
        }
        compute(ch, p);
        WAITL0(); BAR();       // ds ops drained; vmcnt prefetch stays live
    }

    // merge across the 32 column-lanes of each half, tracking 2nd-best
    #pragma unroll
    for (int off = 1; off <= 16; off <<= 1) {
        #pragma unroll
        for (int r = 0; r < 16; ++r) {
            float ov = __shfl_xor(bestv[r], off, 64);
            int   ob = __shfl_xor(bestb[r], off, 64);
            float o2 = __shfl_xor(best2v[r], off, 64);
            float mx = fmaxf(bestv[r], ov);
            best2v[r] = fminf(fminf(best2v[r], o2), mx);
            if (ov < bestv[r] || (ov == bestv[r] && ob < bestb[r])) {
                bestv[r] = ov; bestb[r] = ob;
            }
        }
    }

    // write-out (lanes col==0 of each half own 16 rows each)
    float s0 = 0.f, s1 = 0.f, s2 = 0.f, s3 = 0.f, s4 = 0.f;
    if (col == 0) {
        int* countp = (int*)base + SCR_COUNT;
        int* listp  = (int*)base + SCR_LIST;
        #pragma unroll
        for (int r = 0; r < 16; ++r) {
            const int row_loc = w * 32 + 4 * kg + (r & 3) + 8 * (r >> 2);
            const int grow = r0 + row_loc;
            out[grow] = (float)bestb[r];
            if (best2v[r] - bestv[r] < TAU) {
                int idx = atomicAdd(countp, 1);
                if (idx < LISTCAP) listp[idx] = grow;
            }
            const float m   = mask[grow];
            const float sxx = sxxh[row_loc] + sxxh[128 + row_loc];
            const float d2  = sxx + bestv[r];
            s0 = fmaf(m, d2, s0); s1 += d2; s2 += m;
            s3 += sxh[row_loc] + sxh[128 + row_loc];
            s4 += sxx;
        }
    }
    s0 += __shfl_xor(s0, 32, 64);
    s1 += __shfl_xor(s1, 32, 64);
    s2 += __shfl_xor(s2, 32, 64);
    s3 += __shfl_xor(s3, 32, 64);
    s4 += __shfl_xor(s4, 32, 64);
    if (l == 0) {
        wacc[w * 8 + 0] = s0; wacc[w * 8 + 1] = s1; wacc[w * 8 + 2] = s2;
        wacc[w * 8 + 3] = s3; wacc[w * 8 + 4] = s4;
    }
    WAITL0(); BAR();
    if (tid == 0) {
        float* partials = base + SCR_PART;
        #pragma unroll
        for (int q = 0; q < 5; ++q)
            partials[(size_t)blockIdx.x * 8 + q] =
                wacc[0 * 8 + q] + wacc[1 * 8 + q] + wacc[2 * 8 + q] + wacc[3 * 8 + q];
    }
}

// ------------------------------------------------------------------ fixup ----
// np-f32-exact recompute of flagged near-tie rows (first-occurrence argmin).
__global__ __launch_bounds__(256) void fixup_kernel(const float* __restrict__ x,
                                                    const float* __restrict__ k,
                                                    float* __restrict__ out) {
    __shared__ float xv[C_DIM];
    __shared__ float sxxs;
    __shared__ float redv[4];
    __shared__ int   redb[4];
    const int tid = threadIdx.x;
    const int* count    = (const int*)(out + NT) + SCR_COUNT;
    const int* flaglist = (const int*)(out + NT) + SCR_LIST;
    int cnt = *count;
    if (cnt > LISTCAP) cnt = LISTCAP;

    for (int it = blockIdx.x; it < cnt; it += gridDim.x) {
        const int row = flaglist[it];
        const int n = row >> 13, t = row & (T_DIM - 1);
        if (tid < C_DIM)
            xv[tid] = x[((size_t)n * C_DIM + tid) * T_DIM + t];
        __syncthreads();
        if (tid == 0) sxxs = np_sumsq64(xv);
        __syncthreads();
        const float xx = sxxs;

        float bv = __builtin_inff();
        int   bb = 0x7fffffff;
        for (int b = tid; b < KB; b += 256) {
            const float* kr = k + (size_t)b * C_DIM;
            float dot = 0.f;
            #pragma unroll
            for (int c = 0; c < C_DIM; ++c)
                dot = fmaf(xv[c], kr[c], dot);
            float kk = np_sumsq64(kr);
            float d  = __fadd_rn(__fsub_rn(xx, __fadd_rn(dot, dot)), kk);
            if (d < bv) { bv = d; bb = b; }
        }
        #pragma unroll
        for (int off = 1; off <= 32; off <<= 1) {
            float ov = __shfl_xor(bv, off, 64);
            int   ob = __shfl_xor(bb, off, 64);
            if (ov < bv || (ov == bv && ob < bb)) { bv = ov; bb = ob; }
        }
        const int wid = tid >> 6, lane = tid & 63;
        if (lane == 0) { redv[wid] = bv; redb[wid] = bb; }
        __syncthreads();
        if (tid == 0) {
            float fv = redv[0]; int fb = redb[0];
            #pragma unroll
            for (int wq = 1; wq < 4; ++wq) {
                if (redv[wq] < fv || (redv[wq] == fv && redb[wq] < fb)) {
                    fv = redv[wq]; fb = redb[wq];
                }
            }
            out[row] = (float)fb;
        }
        __syncthreads();
    }
}

// ------------------------------------------------------------- finalize ----
__global__ __launch_bounds__(256) void finalize_kernel(float* __restrict__ out) {
    const float* partials = (out + NT) + SCR_PART;
    const int tid = threadIdx.x;
    double vals[5] = {0, 0, 0, 0, 0};
    for (int i = tid; i < NBLK; i += 256)
        #pragma unroll
        for (int q = 0; q < 5; ++q) vals[q] += (double)partials[(size_t)i * 8 + q];
    #pragma unroll
    for (int off = 1; off <= 32; off <<= 1)
        #pragma unroll
        for (int q = 0; q < 5; ++q) vals[q] += __shfl_xor(vals[q], off, 64);
    __shared__ double sred[4][5];
    const int wid = tid >> 6, lane = tid & 63;
    if (lane == 0)
        for (int q = 0; q < 5; ++q) sred[wid][q] = vals[q];
    __syncthreads();
    if (tid == 0) {
        double cm  = sred[0][0] + sred[1][0] + sred[2][0] + sred[3][0];
        double fs  = sred[0][1] + sred[1][1] + sred[2][1] + sred[3][1];
        double ms  = sred[0][2] + sred[1][2] + sred[2][2] + sred[3][2];
        double sx  = sred[0][3] + sred[1][3] + sred[2][3] + sred[3][3];
        double sxx = sred[0][4] + sred[1][4] + sred[2][4] + sred[3][4];
        double sz  = (double)TOTX;
        out[NT + TOTX + 0] = (float)(cm / (ms * (double)C_DIM));
        out[NT + TOTX + 1] = (float)(fs / (double)NT);
        out[NT + TOTX + 2] = (float)sqrt(fmax(0.0, (sxx - sx * sx / sz) / sz));
    }
}

// --------------------------------------------------------------------- x_d ----
// Runs LAST: overwrites the scratch region with real x_d values.
__global__ __launch_bounds__(256) void xd_kernel(const float* __restrict__ mask,
                                                 const float* __restrict__ k,
                                                 float* __restrict__ out) {
    const int row = blockIdx.x * 256 + threadIdx.x;
    const int n = row >> 13, t = row & (T_DIM - 1);
    const int b = (int)out[row];
    const float m = mask[row];
    const float* kr = k + (size_t)b * C_DIM;
    float* xd = out + NT;
    #pragma unroll
    for (int c = 0; c < C_DIM; ++c)
        xd[((size_t)n * C_DIM + c) * T_DIM + t] = kr[c] * m;
}

// ----------------------------------------------------------------- launch ----
extern "C" void kernel_launch(void* const* d_in, const int* in_sizes, int n_in,
                              void* d_out, int out_size, void* d_ws, size_t ws_size,
                              hipStream_t stream) {
    (void)in_sizes; (void)n_in; (void)out_size; (void)d_ws; (void)ws_size;
    const float* x    = (const float*)d_in[0];
    const float* mask = (const float*)d_in[1];
    const float* k    = (const float*)d_in[2];
    float* out = (float*)d_out;

    kprep_kernel<<<KB / 256, 256, 0, stream>>>(k, out);
    argmin_kernel<<<NBLK, 256, 0, stream>>>(x, mask, out);
    fixup_kernel<<<64, 256, 0, stream>>>(x, k, out);
    finalize_kernel<<<1, 256, 0, stream>>>(out);
    xd_kernel<<<NT / 256, 256, 0, stream>>>(mask, k, out);
}

// Round 10
// 125.419 us; speedup vs baseline: 1.6215x; 1.0690x over previous
//
#include <hip/hip_runtime.h>

#define T_DIM 8192
#define N_DIM 8
#define C_DIM 64
#define KB    2048
#define NT    (N_DIM * T_DIM)        // 65536 rows
#define TOTX  ((size_t)NT * C_DIM)   // 4194304 elements
#define ROWS_BLK 128
#define NBLK  (NT / ROWS_BLK)        // 512 blocks
#define LISTCAP 8192
#define TAU   1e-3f

// Scratch inside out's x_d region (out + NT), overwritten LAST by xd_kernel.
// Offsets in FLOAT units from out+NT:
#define SCR_COUNT 0                   // int
#define SCR_LIST  16                  // int[8192]          -> ends 8208
#define SCR_PART  8448                // float[512][8]      -> ends 12544
#define SCR_KNS   16384               // float[2048]        -> ends 18432
#define SCR_K     32768               // f16x8[16][2048] (512 KB) -> ends 163840

typedef _Float16 half_t;
typedef _Float16 f16x8 __attribute__((ext_vector_type(8)));
typedef float    f32x16 __attribute__((ext_vector_type(16)));

#define WAITL0() asm volatile("s_waitcnt lgkmcnt(0)" ::: "memory")
#define BAR()    __builtin_amdgcn_s_barrier()

// numpy pairwise sum (n=64) of squares for the np-exact fixup.
__device__ __forceinline__ float np_sumsq64(const float* __restrict__ a) {
    float r[8];
    #pragma unroll
    for (int j = 0; j < 8; ++j) r[j] = __fmul_rn(a[j], a[j]);
    #pragma unroll
    for (int i = 8; i < 64; i += 8)
        #pragma unroll
        for (int j = 0; j < 8; ++j)
            r[j] = __fadd_rn(r[j], __fmul_rn(a[i + j], a[i + j]));
    return __fadd_rn(__fadd_rn(__fadd_rn(r[0], r[1]), __fadd_rn(r[2], r[3])),
                     __fadd_rn(__fadd_rn(r[4], r[5]), __fadd_rn(r[6], r[7])));
}

// ------------------------------------------------------------------ k prep ----
// Layout: kscr[ch][0:1024) = hi slots [slot][bin], [1024:2048) = lo slots.
// hi = -2*k_hi (exact), lo = -4096*(k - k_hi) rounded once. Also ||k||^2.
__global__ __launch_bounds__(256) void kprep_kernel(const float* __restrict__ k,
                                                    float* __restrict__ out) {
    float* base = out + NT;
    const int bin = blockIdx.x * 256 + threadIdx.x;   // grid 8 -> 2048
    if (bin == 0) ((int*)base)[SCR_COUNT] = 0;

    float kv[64];
    #pragma unroll
    for (int i = 0; i < 16; ++i)
        *(float4*)&kv[i * 4] = *(const float4*)(k + (size_t)bin * 64 + i * 4);

    float kn = 0.f;
    #pragma unroll
    for (int c = 0; c < 64; ++c) kn = fmaf(kv[c], kv[c], kn);
    base[SCR_KNS + bin] = kn;

    f16x8* kscr = (f16x8*)(base + SCR_K);
    const int ch = bin >> 7, b127 = bin & 127;
    #pragma unroll
    for (int slot = 0; slot < 8; ++slot) {
        f16x8 h8, l8;
        #pragma unroll
        for (int e = 0; e < 8; ++e) {
            float xv = kv[slot * 8 + e];
            half_t hh = (half_t)xv;
            h8[e] = (half_t)(-2.f * (float)hh);
            l8[e] = (half_t)(-4096.f * (xv - (float)hh));
        }
        kscr[(size_t)ch * 2048 + slot * 128 + b127]        = h8;
        kscr[(size_t)ch * 2048 + 1024 + slot * 128 + b127] = l8;
    }
}

// ------------------------------------------------------------------ argmin ----
// 256 threads (4 waves), 128 rows/block. B-fragments loaded DIRECTLY from
// L2-resident kscr into registers (1-tile double buffer) — no k-LDS, no
// barriers in the main loop. A-fragments persistent in registers.
__global__ __launch_bounds__(256, 2) void argmin_kernel(const float* __restrict__ x,
                                                        const float* __restrict__ mask,
                                                        float* __restrict__ out) {
    __shared__ __align__(16) f16x8 xhi_s[1024];       // [8 slots][128 rows]
    __shared__ __align__(16) f16x8 xlo_s[1024];
    __shared__ float kns_s[2048];
    __shared__ float sxh[256], sxxh[256];
    __shared__ float wacc[32];

    float* base = out + NT;
    const int tid = threadIdx.x;
    const int l   = tid & 63, w = tid >> 6;
    const int col = l & 31, kg = l >> 5;
    const int r0  = blockIdx.x * ROWS_BLK;
    const int n   = r0 >> 13;
    const int t0  = r0 & (T_DIM - 1);

    // stage ||k||^2 into LDS (8 per thread)
    #pragma unroll
    for (int i = 0; i < 8; ++i)
        kns_s[i * 256 + tid] = base[SCR_KNS + i * 256 + tid];

    // fused x load + f16 hi/lo split (thread: row = tid&127, c-half = tid>>7)
    {
        const int row = tid & 127, chalf = tid >> 7;
        float xv[32];
        #pragma unroll
        for (int j = 0; j < 32; ++j)
            xv[j] = x[((size_t)n * C_DIM + chalf * 32 + j) * T_DIM + t0 + row];
        float sx = 0.f, sxx = 0.f;
        #pragma unroll
        for (int j = 0; j < 32; ++j) { sx += xv[j]; sxx = fmaf(xv[j], xv[j], sxx); }
        sxh[chalf * 128 + row]  = sx;
        sxxh[chalf * 128 + row] = sxx;
        #pragma unroll
        for (int j4 = 0; j4 < 4; ++j4) {
            f16x8 h8, l8;
            #pragma unroll
            for (int e = 0; e < 8; ++e) {
                float v = xv[j4 * 8 + e];
                half_t hh = (half_t)v;
                h8[e] = hh;
                l8[e] = (half_t)(2048.f * (v - (float)hh));
            }
            const int slot = chalf * 4 + j4;
            xhi_s[slot * 128 + row] = h8;
            xlo_s[slot * 128 + row] = l8;
        }
    }
    WAITL0(); BAR();

    // A fragments (persistent registers)
    const int arow = w * 32 + col;
    f16x8 a_hi[4], a_lo[4];
    #pragma unroll
    for (int s = 0; s < 4; ++s) {
        a_hi[s] = xhi_s[(2 * s + kg) * 128 + arow];
        a_lo[s] = xlo_s[(2 * s + kg) * 128 + arow];
    }

    // lane-based k-fragment base: per tile t, p = kf + (t>>2)*2048 + (t&3)*32
    const f16x8* kf = (const f16x8*)(base + SCR_K) + kg * 128 + col;

    float bestv[16], best2v[16];
    int   bestb[16];
    #pragma unroll
    for (int r = 0; r < 16; ++r) {
        bestv[r] = __builtin_inff(); best2v[r] = __builtin_inff(); bestb[r] = 0;
    }

    f16x8 bhA[4], blA[4], bhB[4], blB[4];

#define LOAD_T(t, BH, BL)                                                   \
    {                                                                       \
        const f16x8* p = kf + (((t) >> 2) * 2048 + ((t) & 3) * 32);         \
        BH[0] = p[0];    BH[1] = p[256];  BH[2] = p[512];  BH[3] = p[768];  \
        BL[0] = p[1024]; BL[1] = p[1280]; BL[2] = p[1536]; BL[3] = p[1792]; \
    }

#define COMP_T(t, BH, BL)                                                   \
    {                                                                       \
        const float kn = kns_s[(t) * 32 + col];                             \
        f32x16 acc1, acc2;                                                  \
        _Pragma("unroll")                                                   \
        for (int r = 0; r < 16; ++r) { acc1[r] = kn; acc2[r] = 0.f; }       \
        _Pragma("unroll")                                                   \
        for (int s = 0; s < 4; ++s) {                                       \
            acc1 = __builtin_amdgcn_mfma_f32_32x32x16_f16(a_hi[s], BH[s], acc1, 0, 0, 0); \
            acc2 = __builtin_amdgcn_mfma_f32_32x32x16_f16(a_hi[s], BL[s], acc2, 0, 0, 0); \
            acc2 = __builtin_amdgcn_mfma_f32_32x32x16_f16(a_lo[s], BH[s], acc2, 0, 0, 0); \
        }                                                                   \
        const int binf = (t) * 32 + col;                                    \
        _Pragma("unroll")                                                   \
        for (int r = 0; r < 16; ++r) {                                      \
            float sv = fmaf(acc2[r], 4.8828125e-4f, acc1[r]);               \
            best2v[r] = fminf(best2v[r], fmaxf(sv, bestv[r]));              \
            if (sv < bestv[r]) { bestv[r] = sv; bestb[r] = binf; }          \
        }                                                                   \
    }

    LOAD_T(0, bhA, blA);
    #pragma unroll 1
    for (int t = 0; t < 64; t += 2) {
        LOAD_T(t + 1, bhB, blB);
        COMP_T(t, bhA, blA);
        if (t + 2 < 64) LOAD_T(t + 2, bhA, blA);
        COMP_T(t + 1, bhB, blB);
    }
#undef LOAD_T
#undef COMP_T

    // merge across the 32 column-lanes of each half, tracking 2nd-best
    #pragma unroll
    for (int off = 1; off <= 16; off <<= 1) {
        #pragma unroll
        for (int r = 0; r < 16; ++r) {
            float ov = __shfl_xor(bestv[r], off, 64);
            int   ob = __shfl_xor(bestb[r], off, 64);
            float o2 = __shfl_xor(best2v[r], off, 64);
            float mx = fmaxf(bestv[r], ov);
            best2v[r] = fminf(fminf(best2v[r], o2), mx);
            if (ov < bestv[r] || (ov == bestv[r] && ob < bestb[r])) {
                bestv[r] = ov; bestb[r] = ob;
            }
        }
    }

    // write-out (lanes col==0 of each half own 16 rows each)
    float s0 = 0.f, s1 = 0.f, s2 = 0.f, s3 = 0.f, s4 = 0.f;
    if (col == 0) {
        int* countp = (int*)base + SCR_COUNT;
        int* listp  = (int*)base + SCR_LIST;
        #pragma unroll
        for (int r = 0; r < 16; ++r) {
            const int row_loc = w * 32 + 4 * kg + (r & 3) + 8 * (r >> 2);
            const int grow = r0 + row_loc;
            out[grow] = (float)bestb[r];
            if (best2v[r] - bestv[r] < TAU) {
                int idx = atomicAdd(countp, 1);
                if (idx < LISTCAP) listp[idx] = grow;
            }
            const float m   = mask[grow];
            const float sxx = sxxh[row_loc] + sxxh[128 + row_loc];
            const float d2  = sxx + bestv[r];
            s0 = fmaf(m, d2, s0); s1 += d2; s2 += m;
            s3 += sxh[row_loc] + sxh[128 + row_loc];
            s4 += sxx;
        }
    }
    s0 += __shfl_xor(s0, 32, 64);
    s1 += __shfl_xor(s1, 32, 64);
    s2 += __shfl_xor(s2, 32, 64);
    s3 += __shfl_xor(s3, 32, 64);
    s4 += __shfl_xor(s4, 32, 64);
    if (l == 0) {
        wacc[w * 8 + 0] = s0; wacc[w * 8 + 1] = s1; wacc[w * 8 + 2] = s2;
        wacc[w * 8 + 3] = s3; wacc[w * 8 + 4] = s4;
    }
    WAITL0(); BAR();
    if (tid == 0) {
        float* partials = base + SCR_PART;
        #pragma unroll
        for (int q = 0; q < 5; ++q)
            partials[(size_t)blockIdx.x * 8 + q] =
                wacc[0 * 8 + q] + wacc[1 * 8 + q] + wacc[2 * 8 + q] + wacc[3 * 8 + q];
    }
}

// ------------------------------------------------------------------ fixup ----
// np-f32-exact recompute of flagged near-tie rows (first-occurrence argmin).
__global__ __launch_bounds__(256) void fixup_kernel(const float* __restrict__ x,
                                                    const float* __restrict__ k,
                                                    float* __restrict__ out) {
    __shared__ float xv[C_DIM];
    __shared__ float sxxs;
    __shared__ float redv[4];
    __shared__ int   redb[4];
    const int tid = threadIdx.x;
    const int* count    = (const int*)(out + NT) + SCR_COUNT;
    const int* flaglist = (const int*)(out + NT) + SCR_LIST;
    int cnt = *count;
    if (cnt > LISTCAP) cnt = LISTCAP;

    for (int it = blockIdx.x; it < cnt; it += gridDim.x) {
        const int row = flaglist[it];
        const int n = row >> 13, t = row & (T_DIM - 1);
        if (tid < C_DIM)
            xv[tid] = x[((size_t)n * C_DIM + tid) * T_DIM + t];
        __syncthreads();
        if (tid == 0) sxxs = np_sumsq64(xv);
        __syncthreads();
        const float xx = sxxs;

        float bv = __builtin_inff();
        int   bb = 0x7fffffff;
        for (int b = tid; b < KB; b += 256) {
            const float* kr = k + (size_t)b * C_DIM;
            float dot = 0.f;
            #pragma unroll
            for (int c = 0; c < C_DIM; ++c)
                dot = fmaf(xv[c], kr[c], dot);
            float kk = np_sumsq64(kr);
            float d  = __fadd_rn(__fsub_rn(xx, __fadd_rn(dot, dot)), kk);
            if (d < bv) { bv = d; bb = b; }
        }
        #pragma unroll
        for (int off = 1; off <= 32; off <<= 1) {
            float ov = __shfl_xor(bv, off, 64);
            int   ob = __shfl_xor(bb, off, 64);
            if (ov < bv || (ov == bv && ob < bb)) { bv = ov; bb = ob; }
        }
        const int wid = tid >> 6, lane = tid & 63;
        if (lane == 0) { redv[wid] = bv; redb[wid] = bb; }
        __syncthreads();
        if (tid == 0) {
            float fv = redv[0]; int fb = redb[0];
            #pragma unroll
            for (int wq = 1; wq < 4; ++wq) {
                if (redv[wq] < fv || (redv[wq] == fv && redb[wq] < fb)) {
                    fv = redv[wq]; fb = redb[wq];
                }
            }
            out[row] = (float)fb;
        }
        __syncthreads();
    }
}

// ------------------------------------------------------------- finalize ----
__global__ __launch_bounds__(256) void finalize_kernel(float* __restrict__ out) {
    const float* partials = (out + NT) + SCR_PART;
    const int tid = threadIdx.x;
    double vals[5] = {0, 0, 0, 0, 0};
    for (int i = tid; i < NBLK; i += 256)
        #pragma unroll
        for (int q = 0; q < 5; ++q) vals[q] += (double)partials[(size_t)i * 8 + q];
    #pragma unroll
    for (int off = 1; off <= 32; off <<= 1)
        #pragma unroll
        for (int q = 0; q < 5; ++q) vals[q] += __shfl_xor(vals[q], off, 64);
    __shared__ double sred[4][5];
    const int wid = tid >> 6, lane = tid & 63;
    if (lane == 0)
        for (int q = 0; q < 5; ++q) sred[wid][q] = vals[q];
    __syncthreads();
    if (tid == 0) {
        double cm  = sred[0][0] + sred[1][0] + sred[2][0] + sred[3][0];
        double fs  = sred[0][1] + sred[1][1] + sred[2][1] + sred[3][1];
        double ms  = sred[0][2] + sred[1][2] + sred[2][2] + sred[3][2];
        double sx  = sred[0][3] + sred[1][3] + sred[2][3] + sred[3][3];
        double sxx = sred[0][4] + sred[1][4] + sred[2][4] + sred[3][4];
        double sz  = (double)TOTX;
        out[NT + TOTX + 0] = (float)(cm / (ms * (double)C_DIM));
        out[NT + TOTX + 1] = (float)(fs / (double)NT);
        out[NT + TOTX + 2] = (float)sqrt(fmax(0.0, (sxx - sx * sx / sz) / sz));
    }
}

// --------------------------------------------------------------------- x_d ----
// Runs LAST: overwrites the scratch region with real x_d values.
__global__ __launch_bounds__(256) void xd_kernel(const float* __restrict__ mask,
                                                 const float* __restrict__ k,
                                                 float* __restrict__ out) {
    const int row = blockIdx.x * 256 + threadIdx.x;
    const int n = row >> 13, t = row & (T_DIM - 1);
    const int b = (int)out[row];
    const float m = mask[row];
    const float* kr = k + (size_t)b * C_DIM;
    float* xd = out + NT;
    #pragma unroll
    for (int c = 0; c < C_DIM; ++c)
        xd[((size_t)n * C_DIM + c) * T_DIM + t] = kr[c] * m;
}

// ----------------------------------------------------------------- launch ----
extern "C" void kernel_launch(void* const* d_in, const int* in_sizes, int n_in,
                              void* d_out, int out_size, void* d_ws, size_t ws_size,
                              hipStream_t stream) {
    (void)in_sizes; (void)n_in; (void)out_size; (void)d_ws; (void)ws_size;
    const float* x    = (const float*)d_in[0];
    const float* mask = (const float*)d_in[1];
    const float* k    = (const float*)d_in[2];
    float* out = (float*)d_out;

    kprep_kernel<<<KB / 256, 256, 0, stream>>>(k, out);
    argmin_kernel<<<NBLK, 256, 0, stream>>>(x, mask, out);
    fixup_kernel<<<64, 256, 0, stream>>>(x, k, out);
    finalize_kernel<<<1, 256, 0, stream>>>(out);
    xd_kernel<<<NT / 256, 256, 0, stream>>>(mask, k, out);
}